// Round 5
// baseline (851.648 us; speedup 1.0000x reference)
//
#include <hip/hip_runtime.h>
#include <math.h>

// Tril2Diff: out[b] = L @ L^T where L is 128x128 lower-triangular scattered
// from x[b] (8256 tril values), diagonal replaced by log1p(exp(d)+1e-12).
//
// Memory-bound: ~672-807 MB real HBM traffic -> ~110-128us floor.
// R1: table-driven scatter (killed VALU bottleneck). R2: swizzled 32KB LDS,
// 5 blocks/CU. R3: NB batch pipelining (null). R4: remove remaining excess
// per-batch work:
//  - triangular k-skip: sub-tile C[R0.., C0..] only needs k <= min(R0,C0)+31
//    -> per-wave compile-time k-limits (MFMA 80->60, ds_read 80->68/batch)
//  - diagonal softplus fused into scatter via flag bit 15 of the offset table
//    (removes the diag pass + one barrier: 2 barriers/batch)
//  - NB=2: table/zero amortization with finer dispatch granularity
// (R4 bench was an infra failure — this is the same candidate re-submitted.)

#define DIM        128
#define NTRIL      8256          // 128*129/2
#define ROW_BYTES  256           // bf16 row, no pad; XOR swizzle kills conflicts
#define NB         2             // batches per block

typedef __bf16 bf16x8 __attribute__((ext_vector_type(8)));
typedef float  f32x16 __attribute__((ext_vector_type(16)));

// ---- compile-time scatter table: flat tril index -> swizzled LDS byte offset
//      bit 15 = diagonal flag (offsets < 32768 so the bit is free) ----
struct RcTab { unsigned short off[NTRIL]; };
static constexpr RcTab make_tab() {
    RcTab t{};
    int idx = 0;
    for (int r = 0; r < DIM; ++r)
        for (int c = 0; c <= r; ++c) {
            unsigned short o = (unsigned short)((r * ROW_BYTES + c * 2) ^ ((r & 7) << 4));
            if (c == r) o |= 0x8000;
            t.off[idx++] = o;
        }
    return t;
}
__device__ const RcTab TBL = make_tab();

__device__ __forceinline__ int rowbase(int r) {   // swizzled base byte of row r
    return (r << 8) ^ ((r & 7) << 4);
}

// one scatter element: softplus if diagonal (rare; divergent branch is cheap)
#define SCAT1(oo, vv)                                                \
    {                                                                \
        float f = (vv);                                              \
        const unsigned short u = (oo);                               \
        if (__builtin_expect((u & 0x8000u) != 0, 0))                 \
            f = log1pf(expf(f) + 1e-12f);                            \
        *(__bf16*)(lbw + (u & 0x7fffu)) = (__bf16)f;                 \
    }

// MFMA for one 64x64 quadrant as 2x2 32x32 tiles, compile-time k-step limits.
// Skipped k-steps only multiply guaranteed-zero (upper-triangle) L entries.
template<int L00, int L01, int L10, int L11>
__device__ __forceinline__ void mfma_quad(
    const char* lb, int ba0, int ba1, int bb0, int bb1, int kb,
    f32x16& acc00, f32x16& acc01, f32x16& acc10, f32x16& acc11)
{
    constexpr int LA0 = (L00 > L01) ? L00 : L01;   // a0 needed through this step
    constexpr int LA1 = (L10 > L11) ? L10 : L11;
    constexpr int LB0 = (L00 > L10) ? L00 : L10;
    constexpr int LB1 = (L01 > L11) ? L01 : L11;
    #pragma unroll
    for (int ks = 0; ks < 8; ++ks) {
        const int koff = ks * 32 + kb;
        bf16x8 a0{}, a1{}, b0{}, b1{};
        if (ks < LA0) a0 = *(const bf16x8*)(lb + (ba0 ^ koff));
        if (ks < LA1) a1 = *(const bf16x8*)(lb + (ba1 ^ koff));
        if (ks < LB0) b0 = *(const bf16x8*)(lb + (bb0 ^ koff));
        if (ks < LB1) b1 = *(const bf16x8*)(lb + (bb1 ^ koff));
        if (ks < L00) acc00 = __builtin_amdgcn_mfma_f32_32x32x16_bf16(a0, b0, acc00, 0, 0, 0);
        if (ks < L01) acc01 = __builtin_amdgcn_mfma_f32_32x32x16_bf16(a0, b1, acc01, 0, 0, 0);
        if (ks < L10) acc10 = __builtin_amdgcn_mfma_f32_32x32x16_bf16(a1, b0, acc10, 0, 0, 0);
        if (ks < L11) acc11 = __builtin_amdgcn_mfma_f32_32x32x16_bf16(a1, b1, acc11, 0, 0, 0);
    }
}

__global__ __launch_bounds__(256) void tril2diff_kernel(
    const float* __restrict__ x, float* __restrict__ out)
{
    __shared__ alignas(16) __bf16 Lsh[DIM * ROW_BYTES / 2];   // 32768 B exactly

    const int tid = threadIdx.x;
    const int b0  = blockIdx.x * NB;

    // ---- batch-invariant scatter offsets: load once, keep in regs ----
    ushort4 o[8], ot;
    #pragma unroll
    for (int i = 0; i < 8; ++i)
        o[i] = *(const ushort4*)(TBL.off + (tid + i * 256) * 4);
    if (tid < 16)                         // tail: 8256/4 = 2064 = 8*256 + 16
        ot = *(const ushort4*)(TBL.off + (2048 + tid) * 4);

    // ---- prefetch batch 0 (latency hides under zero-fill) ----
    float4 v[8], vt;
    {
        const float* xb = x + (size_t)b0 * NTRIL;
        #pragma unroll
        for (int i = 0; i < 8; ++i)
            v[i] = *(const float4*)(xb + (tid + i * 256) * 4);
        if (tid < 16)
            vt = *(const float4*)(xb + (2048 + tid) * 4);
    }

    // ---- zero LDS ONCE: scatter only writes lower-triangle positions, so
    //      the upper-triangle zeros persist across all NB batches ----
    uint4* lz4 = (uint4*)Lsh;
    #pragma unroll
    for (int i = 0; i < 8; ++i)
        lz4[tid + i * 256] = uint4{0u, 0u, 0u, 0u};
    __syncthreads();

    // ---- per-wave MFMA geometry (loop-invariant) ----
    const int lane = tid & 63;
    const int wv   = tid >> 6;
    const int i0   = (wv >> 1) * 64;
    const int j0   = (wv & 1) * 64;
    const int cl   = lane & 31;
    const int hh   = lane >> 5;
    const int kb   = hh * 16;
    const int ba0 = rowbase(i0      + cl);
    const int ba1 = rowbase(i0 + 32 + cl);
    const int bb0 = rowbase(j0      + cl);
    const int bb1 = rowbase(j0 + 32 + cl);

    char*       lbw = (char*)Lsh;
    const char* lb  = (const char*)Lsh;

    for (int n = 0; n < NB; ++n) {
        // ---- scatter regs -> L (bf16, softplus fused on diagonal) ----
        #pragma unroll
        for (int i = 0; i < 8; ++i) {
            SCAT1(o[i].x, v[i].x);
            SCAT1(o[i].y, v[i].y);
            SCAT1(o[i].z, v[i].z);
            SCAT1(o[i].w, v[i].w);
        }
        if (tid < 16) {
            SCAT1(ot.x, vt.x);
            SCAT1(ot.y, vt.y);
            SCAT1(ot.z, vt.z);
            SCAT1(ot.w, vt.w);
        }
        __syncthreads();

        // ---- prefetch batch n+1 into regs (overlaps MFMA + stores) ----
        if (n + 1 < NB) {
            const float* xb = x + (size_t)(b0 + n + 1) * NTRIL;
            #pragma unroll
            for (int i = 0; i < 8; ++i)
                v[i] = *(const float4*)(xb + (tid + i * 256) * 4);
            if (tid < 16)
                vt = *(const float4*)(xb + (2048 + tid) * 4);
        }

        // ---- C = L * L^T via 32x32x16 bf16 MFMA, triangular k-limits ----
        // k-steps for sub-tile (R0,C0): (min(R0,C0)>>4)+2.
        f32x16 acc00 = {0}, acc01 = {0}, acc10 = {0}, acc11 = {0};
        switch (wv) {
        case 0:  // i0=0,  j0=0  : mins {0,0,0,32}   -> 2,2,2,4
            mfma_quad<2, 2, 2, 4>(lb, ba0, ba1, bb0, bb1, kb, acc00, acc01, acc10, acc11);
            break;
        case 1:  // i0=0,  j0=64 : mins {0,0,32,32}  -> 2,2,4,4
            mfma_quad<2, 2, 4, 4>(lb, ba0, ba1, bb0, bb1, kb, acc00, acc01, acc10, acc11);
            break;
        case 2:  // i0=64, j0=0  : mins {0,32,0,32}  -> 2,4,2,4
            mfma_quad<2, 4, 2, 4>(lb, ba0, ba1, bb0, bb1, kb, acc00, acc01, acc10, acc11);
            break;
        default: // i0=64, j0=64 : mins {64,64,64,96}-> 6,6,6,8
            mfma_quad<6, 6, 6, 8>(lb, ba0, ba1, bb0, bb1, kb, acc00, acc01, acc10, acc11);
            break;
        }

        __syncthreads();   // all ds_reads of L done before next scatter overwrites

        // ---- store batch n (overlaps next iteration's scatter) ----
        // C/D layout: col=lane&31, row=(reg&3)+8*(reg>>2)+4*(lane>>5).
        // Each 32-lane half-wave writes 128 contiguous bytes per store.
        float* ob = out + (size_t)(b0 + n) * (DIM * DIM);
        #pragma unroll
        for (int reg = 0; reg < 16; ++reg) {
            const int row = (reg & 3) + 8 * (reg >> 2) + 4 * hh;
            ob[(i0      + row) * DIM + j0      + cl] = acc00[reg];
            ob[(i0      + row) * DIM + j0 + 32 + cl] = acc01[reg];
            ob[(i0 + 32 + row) * DIM + j0      + cl] = acc10[reg];
            ob[(i0 + 32 + row) * DIM + j0 + 32 + cl] = acc11[reg];
        }
    }
}

extern "C" void kernel_launch(void* const* d_in, const int* in_sizes, int n_in,
                              void* d_out, int out_size, void* d_ws, size_t ws_size,
                              hipStream_t stream) {
    const float* x = (const float*)d_in[0];
    float* out = (float*)d_out;
    const int batch = in_sizes[0] / NTRIL;   // 8192
    tril2diff_kernel<<<batch / NB, 256, 0, stream>>>(x, out);
}